// Round 7
// baseline (233.432 us; speedup 1.0000x reference)
//
#include <hip/hip_runtime.h>
#include <hip/hip_bf16.h>
#include <stdint.h>

// RecurrentReadout: x[16,256,1024,8,8] -> spatial mean -> linear (W[1024,1024],b) -> diag recurrence over T.
// R7: GEMM = 64x64 tile (R3's measured occupancy win, 4 blocks/CU) + dbuf 2-phase (R6's measured
// pipeline win) + XCD-chunked block swizzle (per-XCD L2 footprint: 1MB A-panel + 2MB W < 4MB L2).
// Kernels: k_mean (1GiB read @ BW ceiling, W->bf16 piggybacked) ; k_gemm (u+b -> d_out) ; k_scan.

typedef __attribute__((ext_vector_type(8))) short bf16x8;   // 8 bf16 = 4 VGPRs (MFMA A/B frag)
typedef __attribute__((ext_vector_type(4))) float f32x4;    // MFMA C/D frag

__device__ __forceinline__ unsigned short f2bf(float f) {
  union { float f; unsigned int u; } c; c.f = f;
  unsigned int u = c.u;
  return (unsigned short)((u + 0x7FFFu + ((u >> 16) & 1u)) >> 16);  // RNE
}

// ---------------- spatial mean (+ W fp32->bf16 piggybacked) ----------------
// 16 lanes per segment, float4 each (4KB contiguous per block-iter). shfl_xor tree in 16-lane groups.
// Unsynchronized streaming keeps it at the HBM read ceiling (R5 lesson: no barriers here).
__global__ __launch_bounds__(256) void k_mean(const float* __restrict__ x,
                                              unsigned short* __restrict__ xm,
                                              const float* __restrict__ W,
                                              unsigned short* __restrict__ Wb) {
  const int tid = threadIdx.x;
  // piggyback: first 262144 threads convert one float4 of W (1M elems total)
  const int wi = blockIdx.x * 256 + tid;
  if (wi < 262144) {
    float4 v = *(const float4*)(W + wi * 4);
    ushort4 o;
    o.x = f2bf(v.x); o.y = f2bf(v.y); o.z = f2bf(v.z); o.w = f2bf(v.w);
    *(ushort4*)(Wb + wi * 4) = o;
  }
  const int sub = tid & 15;
  const int grp = tid >> 4;
  for (int base = blockIdx.x * 16; base < (1 << 22); base += gridDim.x * 16) {
    int seg = base + grp;
    const float4 v = *(const float4*)(x + (long)seg * 64 + sub * 4);
    float s = v.x + v.y + v.z + v.w;
    s += __shfl_xor(s, 1);
    s += __shfl_xor(s, 2);
    s += __shfl_xor(s, 4);
    s += __shfl_xor(s, 8);
    if (sub == 0) xm[seg] = f2bf(s * 0.015625f);
  }
}

// ---------------- bf16 GEMM: U[4096,1024] = xm[4096,1024] * Wb[1024,1024]^T + b ----------------
// 64x64 block tile, BK=64, 4 waves (2x2), wave tile 32x32 (2x2 frags, 8 MFMA : 8 ds_read per iter).
// Grid 1024 (1-D) = 4 blocks/CU; LDS 32 KB dbuf. 2-phase: { stage(t+1) [4 GLDS, unwaited] ;
// compute(t) ; __syncthreads (vmcnt drain — hidden by 3 co-resident blocks) }.
// XCD swizzle: xcd = bid&7, nb = xcd*128 + bid/8 -> each XCD gets 8 contiguous m-panels x all n.
// LDS rows are 128 B; phys 16B-slot = kslot ^ (row&7): each 8-lane read group covers all 8 slots
// (all 32 banks) exactly once -> floor-rate b128. Swizzle applied on the GLOBAL source
// (global_load_lds dest must stay linear, rule #21) and identically on the ds_read side.
#define GLDS16(g, l) \
  __builtin_amdgcn_global_load_lds((const __attribute__((address_space(1))) void*)(g), \
                                   (__attribute__((address_space(3))) void*)(l), 16, 0, 0)

__global__ __launch_bounds__(256) void k_gemm(const unsigned short* __restrict__ A,
                                              const unsigned short* __restrict__ Bm,
                                              const float* __restrict__ bias,
                                              float* __restrict__ U) {
  __shared__ unsigned short lds[2][8192];  // per buf: A[64][64] (4096 sh) + B[64][64] (4096 sh) = 16 KB
  const int bid = blockIdx.x;
  const int nb  = (bid & 7) * 128 + (bid >> 3);  // XCD-chunked, bijective (1024 = 8*128)
  const int m0  = (nb >> 4) * 64;                // 64 m-tiles
  const int n0  = (nb & 15) * 64;                // 16 n-tiles

  const int tid  = threadIdx.x;
  const int lane = tid & 63;
  const int wid  = tid >> 6;
  const int wr = wid >> 1, wc = wid & 1;   // wave tile: rows [wr*32,+32), cols [wc*32,+32)

  f32x4 acc[2][2] = {};

  const int srow8  = tid >> 3;             // staging row 0..31 within a 32-row round
  const int sslot8 = tid & 7;              // 16B slot 0..7 within a 128B row
  const int gkoff  = (sslot8 ^ (srow8 & 7)) << 3;  // pre-swizzled k-offset (elements)
  const int r16    = lane & 15;
  const int kb     = lane >> 4;            // 0..3

  const unsigned short* ag0 = A  + (long)(m0 + srow8) * 1024 + gkoff;
  const unsigned short* ag1 = A  + (long)(m0 + 32 + srow8) * 1024 + gkoff;  // (r+32)&7 == r&7
  const unsigned short* bg0 = Bm + (long)(n0 + srow8) * 1024 + gkoff;
  const unsigned short* bg1 = Bm + (long)(n0 + 32 + srow8) * 1024 + gkoff;

  auto stage = [&](int t) {
    const int k0 = t * 64;
    char* Ab = (char*)&lds[t & 1][0];
    char* Bb = (char*)&lds[t & 1][4096];
    GLDS16(ag0 + k0, Ab + tid * 16);
    GLDS16(ag1 + k0, Ab + tid * 16 + 4096);
    GLDS16(bg0 + k0, Bb + tid * 16);
    GLDS16(bg1 + k0, Bb + tid * 16 + 4096);
  };

  auto compute = [&](int t) {
    const unsigned short* Ab = &lds[t & 1][0];
    const unsigned short* Bb = &lds[t & 1][4096];
    bf16x8 af[2][2], bf_[2][2];
#pragma unroll
    for (int ks = 0; ks < 2; ks++) {
#pragma unroll
      for (int i = 0; i < 2; i++) {
        const int rr = wr * 32 + i * 16 + r16;
        af[ks][i] = *(const bf16x8*)(Ab + rr * 64 + (((ks * 4 + kb) ^ (rr & 7)) << 3));
      }
#pragma unroll
      for (int j = 0; j < 2; j++) {
        const int cc = wc * 32 + j * 16 + r16;
        bf_[ks][j] = *(const bf16x8*)(Bb + cc * 64 + (((ks * 4 + kb) ^ (cc & 7)) << 3));
      }
    }
#pragma unroll
    for (int ks = 0; ks < 2; ks++)
#pragma unroll
      for (int i = 0; i < 2; i++)
#pragma unroll
        for (int j = 0; j < 2; j++)
          acc[i][j] = __builtin_amdgcn_mfma_f32_16x16x32_bf16(af[ks][i], bf_[ks][j], acc[i][j], 0, 0, 0);
  };

  stage(0);
  __syncthreads();
#pragma unroll 1
  for (int t = 0; t < 16; t++) {
    if (t < 15) stage(t + 1);   // issue next tile's loads BEFORE this tile's compute
    compute(t);
    __syncthreads();            // drains vmcnt; stage(t+1) had the whole compute phase to land
  }

  // C/D layout: col = lane&15 (n), row = (lane>>4)*4 + q (m)  [measured m89/m91]
  const int orow = (lane >> 4) * 4;
  const int ocol = lane & 15;
  const float bb[2] = { bias[n0 + wc * 32 + ocol], bias[n0 + wc * 32 + 16 + ocol] };
#pragma unroll
  for (int i = 0; i < 2; i++)
#pragma unroll
    for (int j = 0; j < 2; j++) {
      const int m = m0 + wr * 32 + i * 16 + orow;
      const int n = n0 + wc * 32 + j * 16 + ocol;
#pragma unroll
      for (int q = 0; q < 4; q++)
        U[(long)(m + q) * 1024 + n] = acc[i][j][q] + bb[j];
    }
}

// ---------------- diag recurrence over T, in-place in d_out ----------------
// r_t = alpha*r_{t-1} + u'_t (u' = u+b from GEMM epilogue); r_seq overwrites u'; r_final appended.
// 256 waves (1/CU), latency-bound: two 64-reg buffers, group g+1's loads issued before group g's
// serial FMA chain. Static indexing only (rule #20).
template<int G>
__device__ __forceinline__ void scan_load(float* buf, const float* p) {
#pragma unroll
  for (int i = 0; i < 64; i++) buf[i] = p[G * 65536 + i * 1024];
}
template<int G>
__device__ __forceinline__ void scan_proc(float* buf, float* p, float a, float& r) {
#pragma unroll
  for (int i = 0; i < 64; i++) { r = fmaf(a, r, buf[i]); buf[i] = r; }
#pragma unroll
  for (int i = 0; i < 64; i++) p[G * 65536 + i * 1024] = buf[i];
}

__global__ __launch_bounds__(64) void k_scan(const float* __restrict__ r0,
                                             const float* __restrict__ alpha,
                                             float* __restrict__ out) {
  const int gid = blockIdx.x * 64 + threadIdx.x;  // 0..16383 = b*1024 + o
  const int o = gid & 1023;
  const float a = alpha[o];
  float r = r0[gid];
  float* p = out + (long)(gid >> 10) * (256L * 1024) + o;
  float bufA[64], bufB[64];
  scan_load<0>(bufA, p);
  scan_load<1>(bufB, p); scan_proc<0>(bufA, p, a, r);
  scan_load<2>(bufA, p); scan_proc<1>(bufB, p, a, r);
  scan_load<3>(bufB, p); scan_proc<2>(bufA, p, a, r);
  scan_proc<3>(bufB, p, a, r);
  out[(1 << 22) + gid] = r;  // r_final
}

extern "C" void kernel_launch(void* const* d_in, const int* in_sizes, int n_in,
                              void* d_out, int out_size, void* d_ws, size_t ws_size,
                              hipStream_t stream) {
  const float* x     = (const float*)d_in[0];
  const float* r0    = (const float*)d_in[1];
  const float* W     = (const float*)d_in[2];
  const float* b     = (const float*)d_in[3];
  const float* alpha = (const float*)d_in[4];
  float* out = (float*)d_out;

  unsigned short* xm = (unsigned short*)d_ws;                        // 8 MiB: [4096][1024] bf16
  unsigned short* Wb = (unsigned short*)((char*)d_ws + (8u << 20));  // 2 MiB: [1024][1024] bf16

  k_mean<<<2048, 256, 0, stream>>>(x, xm, W, Wb);
  k_gemm<<<1024, 256, 0, stream>>>(xm, Wb, b, out);
  k_scan<<<256, 64, 0, stream>>>(r0, alpha, out);
}

// Round 8
// 231.145 us; speedup vs baseline: 1.0099x; 1.0099x over previous
//
#include <hip/hip_runtime.h>
#include <hip/hip_bf16.h>
#include <stdint.h>

// RecurrentReadout: x[16,256,1024,8,8] -> spatial mean -> linear (W[1024,1024],b) -> diag recurrence over T.
// R8 = R6 (best, 229.8us) + ONE change: XCD-chunked block swizzle on the GEMM.
// Theory: R6's GEMM re-reads A 16x + W 32x = ~192MB with no XCD locality -> mostly HBM (~30us).
// Swizzle gives XCD k m-tiles [4k,4k+4) x all 16 n-tiles: footprint 4 A-panels (1MB) + W (2MB) = 3MB
// < 4MiB private L2, with all 64 blocks/XCD co-resident -> operand re-reads become L2 hits.
// Kernels: k_mean (1GiB read @ BW ceiling, W->bf16 piggybacked) ; k_gemm (u+b -> d_out) ; k_scan.

typedef __attribute__((ext_vector_type(8))) short bf16x8;   // 8 bf16 = 4 VGPRs (MFMA A/B frag)
typedef __attribute__((ext_vector_type(4))) float f32x4;    // MFMA C/D frag

__device__ __forceinline__ unsigned short f2bf(float f) {
  union { float f; unsigned int u; } c; c.f = f;
  unsigned int u = c.u;
  return (unsigned short)((u + 0x7FFFu + ((u >> 16) & 1u)) >> 16);  // RNE
}

// ---------------- spatial mean (+ W fp32->bf16 piggybacked) ----------------
// 16 lanes per segment, float4 each (4KB contiguous per block-iter). shfl_xor tree in 16-lane groups.
// Unsynchronized streaming keeps it at the HBM read ceiling (R5 lesson: no barriers here).
__global__ __launch_bounds__(256) void k_mean(const float* __restrict__ x,
                                              unsigned short* __restrict__ xm,
                                              const float* __restrict__ W,
                                              unsigned short* __restrict__ Wb) {
  const int tid = threadIdx.x;
  // piggyback: first 262144 threads convert one float4 of W (1M elems total)
  const int wi = blockIdx.x * 256 + tid;
  if (wi < 262144) {
    float4 v = *(const float4*)(W + wi * 4);
    ushort4 o;
    o.x = f2bf(v.x); o.y = f2bf(v.y); o.z = f2bf(v.z); o.w = f2bf(v.w);
    *(ushort4*)(Wb + wi * 4) = o;
  }
  const int sub = tid & 15;
  const int grp = tid >> 4;
  for (int base = blockIdx.x * 16; base < (1 << 22); base += gridDim.x * 16) {
    int seg = base + grp;
    const float4 v = *(const float4*)(x + (long)seg * 64 + sub * 4);
    float s = v.x + v.y + v.z + v.w;
    s += __shfl_xor(s, 1);
    s += __shfl_xor(s, 2);
    s += __shfl_xor(s, 4);
    s += __shfl_xor(s, 8);
    if (sub == 0) xm[seg] = f2bf(s * 0.015625f);
  }
}

// ---------------- bf16 GEMM: U[4096,1024] = xm[4096,1024] * Wb[1024,1024]^T + b ----------------
// 128x64 block tile, BK=64, 4 waves (2x2), wave tile 64x32 (4x2 frags, 16 MFMA : 12 ds_read per iter).
// T3 2-phase: lds[2] double buffer; per iter { STAGE(t+1) [6 GLDS, unwaited] ; compute(t) ;
// __syncthreads (vmcnt drain, hidden by co-resident block) }. Grid 512 1-D = 2 blocks/CU.
// XCD swizzle: xcd = bid&7 (consecutive bids round-robin XCDs), nb = xcd*64 + bid/8;
// m-tile = nb>>4, n-tile = nb&15 -> XCD k owns m-tiles [4k,4k+4) x all n.
// LDS rows 128 B; phys 16B-slot = kslot ^ (row&7): frag b128 reads cover all 8 slot-groups
// evenly (conflict-free). Swizzle on GLOBAL source (GLDS dest linear, rule #21) + same on ds_read.
#define GLDS16(g, l) \
  __builtin_amdgcn_global_load_lds((const __attribute__((address_space(1))) void*)(g), \
                                   (__attribute__((address_space(3))) void*)(l), 16, 0, 0)

__global__ __launch_bounds__(256) void k_gemm(const unsigned short* __restrict__ A,
                                              const unsigned short* __restrict__ Bm,
                                              const float* __restrict__ bias,
                                              float* __restrict__ U) {
  __shared__ unsigned short lds[2][12288];  // per buf: A[128][64] (8192 sh) + B[64][64] (4096 sh) = 24 KB
  const int bid = blockIdx.x;
  const int nb  = (bid & 7) * 64 + (bid >> 3);   // XCD-chunked, bijective (512 = 8*64)
  const int m0  = (nb >> 4) * 128;               // 32 m-tiles
  const int n0  = (nb & 15) * 64;                // 16 n-tiles

  const int tid  = threadIdx.x;
  const int lane = tid & 63;
  const int wid  = tid >> 6;
  const int wr = wid >> 1, wc = wid & 1;   // wave tile: rows [wr*64,+64), cols [wc*32,+32)

  f32x4 acc[4][2] = {};

  const int srow8  = tid >> 3;             // staging row 0..31 within a 32-row round
  const int sslot8 = tid & 7;              // 16B slot 0..7 within a 128B row
  const int gkoff  = (sslot8 ^ (srow8 & 7)) << 3;  // pre-swizzled k-offset (elements); rounds %8-aligned
  const int r16    = lane & 15;
  const int kb     = lane >> 4;            // 0..3

  const unsigned short* ag[4];
  const unsigned short* bg[2];
#pragma unroll
  for (int ra = 0; ra < 4; ra++) ag[ra] = A  + (long)(m0 + ra * 32 + srow8) * 1024 + gkoff;
#pragma unroll
  for (int rb = 0; rb < 2; rb++) bg[rb] = Bm + (long)(n0 + rb * 32 + srow8) * 1024 + gkoff;

  auto stage = [&](int t) {
    const int k0 = t * 64;
    char* Ab = (char*)&lds[t & 1][0];
    char* Bb = (char*)&lds[t & 1][8192];
#pragma unroll
    for (int ra = 0; ra < 4; ra++) GLDS16(ag[ra] + k0, Ab + tid * 16 + ra * 4096);
#pragma unroll
    for (int rb = 0; rb < 2; rb++) GLDS16(bg[rb] + k0, Bb + tid * 16 + rb * 4096);
  };

  auto compute = [&](int t) {
    const unsigned short* Ab = &lds[t & 1][0];
    const unsigned short* Bb = &lds[t & 1][8192];
    bf16x8 af[2][4], bf_[2][2];
#pragma unroll
    for (int ks = 0; ks < 2; ks++) {
#pragma unroll
      for (int i = 0; i < 4; i++) {
        const int rr = wr * 64 + i * 16 + r16;
        af[ks][i] = *(const bf16x8*)(Ab + rr * 64 + (((ks * 4 + kb) ^ (rr & 7)) << 3));
      }
#pragma unroll
      for (int j = 0; j < 2; j++) {
        const int cc = wc * 32 + j * 16 + r16;
        bf_[ks][j] = *(const bf16x8*)(Bb + cc * 64 + (((ks * 4 + kb) ^ (cc & 7)) << 3));
      }
    }
#pragma unroll
    for (int ks = 0; ks < 2; ks++)
#pragma unroll
      for (int i = 0; i < 4; i++)
#pragma unroll
        for (int j = 0; j < 2; j++)
          acc[i][j] = __builtin_amdgcn_mfma_f32_16x16x32_bf16(af[ks][i], bf_[ks][j], acc[i][j], 0, 0, 0);
  };

  stage(0);
  __syncthreads();
#pragma unroll 1
  for (int t = 0; t < 16; t++) {
    if (t < 15) stage(t + 1);   // issue next tile's loads BEFORE this tile's compute
    compute(t);
    __syncthreads();            // drains vmcnt; stage(t+1) had the whole compute phase to land
  }

  // C/D layout: col = lane&15 (n), row = (lane>>4)*4 + q (m)  [measured m89/m91]
  const int orow = (lane >> 4) * 4;
  const int ocol = lane & 15;
  const float bb[2] = { bias[n0 + wc * 32 + ocol], bias[n0 + wc * 32 + 16 + ocol] };
#pragma unroll
  for (int i = 0; i < 4; i++)
#pragma unroll
    for (int j = 0; j < 2; j++) {
      const int m = m0 + wr * 64 + i * 16 + orow;
      const int n = n0 + wc * 32 + j * 16 + ocol;
#pragma unroll
      for (int q = 0; q < 4; q++)
        U[(long)(m + q) * 1024 + n] = acc[i][j][q] + bb[j];
    }
}

// ---------------- diag recurrence over T, in-place in d_out ----------------
// r_t = alpha*r_{t-1} + u'_t (u' = u+b from GEMM epilogue); r_seq overwrites u'; r_final appended.
// 256 waves (1/CU), latency-bound: two 64-reg buffers, group g+1's loads issued before group g's
// serial FMA chain. Static indexing only (rule #20).
template<int G>
__device__ __forceinline__ void scan_load(float* buf, const float* p) {
#pragma unroll
  for (int i = 0; i < 64; i++) buf[i] = p[G * 65536 + i * 1024];
}
template<int G>
__device__ __forceinline__ void scan_proc(float* buf, float* p, float a, float& r) {
#pragma unroll
  for (int i = 0; i < 64; i++) { r = fmaf(a, r, buf[i]); buf[i] = r; }
#pragma unroll
  for (int i = 0; i < 64; i++) p[G * 65536 + i * 1024] = buf[i];
}

__global__ __launch_bounds__(64) void k_scan(const float* __restrict__ r0,
                                             const float* __restrict__ alpha,
                                             float* __restrict__ out) {
  const int gid = blockIdx.x * 64 + threadIdx.x;  // 0..16383 = b*1024 + o
  const int o = gid & 1023;
  const float a = alpha[o];
  float r = r0[gid];
  float* p = out + (long)(gid >> 10) * (256L * 1024) + o;
  float bufA[64], bufB[64];
  scan_load<0>(bufA, p);
  scan_load<1>(bufB, p); scan_proc<0>(bufA, p, a, r);
  scan_load<2>(bufA, p); scan_proc<1>(bufB, p, a, r);
  scan_load<3>(bufB, p); scan_proc<2>(bufA, p, a, r);
  scan_proc<3>(bufB, p, a, r);
  out[(1 << 22) + gid] = r;  // r_final
}

extern "C" void kernel_launch(void* const* d_in, const int* in_sizes, int n_in,
                              void* d_out, int out_size, void* d_ws, size_t ws_size,
                              hipStream_t stream) {
  const float* x     = (const float*)d_in[0];
  const float* r0    = (const float*)d_in[1];
  const float* W     = (const float*)d_in[2];
  const float* b     = (const float*)d_in[3];
  const float* alpha = (const float*)d_in[4];
  float* out = (float*)d_out;

  unsigned short* xm = (unsigned short*)d_ws;                        // 8 MiB: [4096][1024] bf16
  unsigned short* Wb = (unsigned short*)((char*)d_ws + (8u << 20));  // 2 MiB: [1024][1024] bf16

  k_mean<<<2048, 256, 0, stream>>>(x, xm, W, Wb);
  k_gemm<<<512, 256, 0, stream>>>(xm, Wb, b, out);
  k_scan<<<256, 64, 0, stream>>>(r0, alpha, out);
}

// Round 9
// 228.306 us; speedup vs baseline: 1.0225x; 1.0124x over previous
//
#include <hip/hip_runtime.h>
#include <hip/hip_bf16.h>
#include <stdint.h>

// RecurrentReadout: x[16,256,1024,8,8] -> spatial mean -> linear (W[1024,1024],b) -> diag recurrence over T.
// R9: FUSE GEMM+SCAN. Block = (b, 64-col n-tile): 256 blocks (1/CU), 4 waves; wave w owns t in
// [64w,64w+64) x 64 cols. GEMM: full A-panel [256][64] + B [64][64] staged per BK=64 (dbuf 2-phase).
// Scan in-register in the epilogue: q-chain (FMA) -> h-scan (2 weighted shfl_up) -> i-chain
// (broadcast shfl) -> cross-wave combine via LDS F[4][64] with alpha^64 weights.
// Deletes the 16MB U-read + scan launch + its 1-wave/CU latency exposure.
// k_mean unchanged (1 GiB read @ BW ceiling; R5 lesson: keep it barrier-free).

typedef __attribute__((ext_vector_type(8))) short bf16x8;   // 8 bf16 = 4 VGPRs (MFMA A/B frag)
typedef __attribute__((ext_vector_type(4))) float f32x4;    // MFMA C/D frag

__device__ __forceinline__ unsigned short f2bf(float f) {
  union { float f; unsigned int u; } c; c.f = f;
  unsigned int u = c.u;
  return (unsigned short)((u + 0x7FFFu + ((u >> 16) & 1u)) >> 16);  // RNE
}

// ---------------- spatial mean (+ W fp32->bf16 piggybacked) ----------------
__global__ __launch_bounds__(256) void k_mean(const float* __restrict__ x,
                                              unsigned short* __restrict__ xm,
                                              const float* __restrict__ W,
                                              unsigned short* __restrict__ Wb) {
  const int tid = threadIdx.x;
  const int wi = blockIdx.x * 256 + tid;
  if (wi < 262144) {
    float4 v = *(const float4*)(W + wi * 4);
    ushort4 o;
    o.x = f2bf(v.x); o.y = f2bf(v.y); o.z = f2bf(v.z); o.w = f2bf(v.w);
    *(ushort4*)(Wb + wi * 4) = o;
  }
  const int sub = tid & 15;
  const int grp = tid >> 4;
  for (int base = blockIdx.x * 16; base < (1 << 22); base += gridDim.x * 16) {
    int seg = base + grp;
    const float4 v = *(const float4*)(x + (long)seg * 64 + sub * 4);
    float s = v.x + v.y + v.z + v.w;
    s += __shfl_xor(s, 1);
    s += __shfl_xor(s, 2);
    s += __shfl_xor(s, 4);
    s += __shfl_xor(s, 8);
    if (sub == 0) xm[seg] = f2bf(s * 0.015625f);
  }
}

// ---------------- fused GEMM + scan ----------------
#define GLDS16(g, l) \
  __builtin_amdgcn_global_load_lds((const __attribute__((address_space(1))) void*)(g), \
                                   (__attribute__((address_space(3))) void*)(l), 16, 0, 0)

__global__ __launch_bounds__(256, 1) void k_gemmscan(const unsigned short* __restrict__ A,
                                                     const unsigned short* __restrict__ Bm,
                                                     const float* __restrict__ bias,
                                                     const float* __restrict__ r0,
                                                     const float* __restrict__ alpha,
                                                     float* __restrict__ out) {
  __shared__ unsigned short lds[2][20480];  // per buf: A[256][64] (16384 sh, 32KB) + B[64][64] (4096 sh, 8KB)
  const int bid = blockIdx.x;
  const int nb  = (bid & 7) * 32 + (bid >> 3);  // XCD-chunked bijective (256 = 8*32): XCD owns 2 b x 16 nt
  const int b   = nb >> 4;
  const int n0  = (nb & 15) * 64;
  const int m0  = b * 256;

  const int tid  = threadIdx.x;
  const int lane = tid & 63;
  const int w    = tid >> 6;       // wave id: t-range [64w, 64w+64)
  const int r16  = lane & 15;
  const int kb   = lane >> 4;      // k-block in MFMA frag
  const int h    = lane >> 4;      // scan h-group (t = 16i + 4h + q)

  f32x4 acc[4][4] = {};            // [i: m-frag][j: n-frag]

  const int srow8  = tid >> 3;     // 0..31
  const int sslot8 = tid & 7;
  const int gkoff  = (sslot8 ^ (srow8 & 7)) << 3;  // pre-swizzled k-offset; row&7 invariant per 32-row round

  const unsigned short* ag[8];
  const unsigned short* bg[2];
#pragma unroll
  for (int ra = 0; ra < 8; ra++) ag[ra] = A  + (long)(m0 + ra * 32 + srow8) * 1024 + gkoff;
#pragma unroll
  for (int rb = 0; rb < 2; rb++) bg[rb] = Bm + (long)(n0 + rb * 32 + srow8) * 1024 + gkoff;

  auto stage = [&](int t) {
    const int k0 = t * 64;
    char* Ab = (char*)&lds[t & 1][0];
    char* Bb = (char*)&lds[t & 1][16384];
#pragma unroll
    for (int ra = 0; ra < 8; ra++) GLDS16(ag[ra] + k0, Ab + tid * 16 + ra * 4096);
#pragma unroll
    for (int rb = 0; rb < 2; rb++) GLDS16(bg[rb] + k0, Bb + tid * 16 + rb * 4096);
  };

  auto compute = [&](int t) {
    const unsigned short* Ab = &lds[t & 1][0];
    const unsigned short* Bb = &lds[t & 1][16384];
    bf16x8 af[2][4], bf_[2][4];
#pragma unroll
    for (int ks = 0; ks < 2; ks++) {
#pragma unroll
      for (int i = 0; i < 4; i++) {
        const int rr = w * 64 + i * 16 + r16;
        af[ks][i] = *(const bf16x8*)(Ab + rr * 64 + (((ks * 4 + kb) ^ (rr & 7)) << 3));
      }
#pragma unroll
      for (int j = 0; j < 4; j++) {
        const int cc = j * 16 + r16;
        bf_[ks][j] = *(const bf16x8*)(Bb + cc * 64 + (((ks * 4 + kb) ^ (cc & 7)) << 3));
      }
    }
#pragma unroll
    for (int ks = 0; ks < 2; ks++)
#pragma unroll
      for (int i = 0; i < 4; i++)
#pragma unroll
        for (int j = 0; j < 4; j++)
          acc[i][j] = __builtin_amdgcn_mfma_f32_16x16x32_bf16(af[ks][i], bf_[ks][j], acc[i][j], 0, 0, 0);
  };

  stage(0);
  __syncthreads();
#pragma unroll 1
  for (int t = 0; t < 16; t++) {
    if (t < 15) stage(t + 1);
    compute(t);
    __syncthreads();
  }

  // ---- in-register scan over t = 64w + 16i + 4h + q (C/D: col=lane&15, row=(lane>>4)*4+q) ----
  // alpha powers per j (col = n0 + 16j + r16)
  float a1[4], a2[4], a3[4], a4[4], a8[4], a12[4], a16[4], a64[4], p4h[4], r0v[4], Cw[4];
#pragma unroll
  for (int j = 0; j < 4; j++) {
    const int col = n0 + j * 16 + r16;
    const float a = alpha[col];
    a1[j] = a; a2[j] = a * a; a3[j] = a2[j] * a; a4[j] = a2[j] * a2[j];
    a8[j] = a4[j] * a4[j]; a12[j] = a8[j] * a4[j]; a16[j] = a8[j] * a8[j];
    const float a32 = a16[j] * a16[j]; a64[j] = a32 * a32;
    p4h[j] = (h == 0) ? 1.f : (h == 1) ? a4[j] : (h == 2) ? a8[j] : a12[j];
    r0v[j] = r0[b * 1024 + col];
    const float bb = bias[col];
    Cw[j] = 0.f;
    // local (wave-internal) scan for this column group
#pragma unroll
    for (int i = 0; i < 4; i++) {
      const float u0 = acc[i][j][0] + bb, u1 = acc[i][j][1] + bb;
      const float u2 = acc[i][j][2] + bb, u3 = acc[i][j][3] + bb;
      const float l0 = u0;
      const float l1 = fmaf(a1[j], l0, u1);
      const float l2 = fmaf(a1[j], l1, u2);
      const float l3 = fmaf(a1[j], l2, u3);
      // weighted Hillis-Steele over h: x_h = sum_{g<=h} a^{4(h-g)} S_g, S = l3
      float xv = l3;
      float t1 = __shfl_up(xv, 16); if (h >= 1) xv = fmaf(a4[j], t1, xv);
      float t2 = __shfl_up(xv, 32); if (h >= 2) xv = fmaf(a8[j], t2, xv);
      float P  = __shfl_up(xv, 16); if (h == 0) P = 0.f;     // exclusive over h
      const float G = fmaf(p4h[j], Cw[j], P);                 // carry into (i,h)
      acc[i][j][0] = fmaf(a1[j], G, l0);
      acc[i][j][1] = fmaf(a2[j], G, l1);
      acc[i][j][2] = fmaf(a3[j], G, l2);
      acc[i][j][3] = fmaf(a4[j], G, l3);
      const float xe = __shfl(xv, r16 + 48);                  // inclusive at h=3 (broadcast)
      Cw[j] = fmaf(a16[j], Cw[j], xe);                        // carry into frag i+1
    }
  }

  // ---- cross-wave combine: R_{w-1} = a^{64w} r0 + sum_{v<w} a^{64(w-1-v)} C_v ----
  float* F = (float*)&lds[0][0];  // [4][64]; safe: last k-loop barrier passed, scan was reg-only
  if (h == 0) {
#pragma unroll
    for (int j = 0; j < 4; j++) F[w * 64 + j * 16 + r16] = Cw[j];
  }
  __syncthreads();
  float R[4];
#pragma unroll
  for (int j = 0; j < 4; j++) {
    R[j] = r0v[j];
    for (int v = 0; v < w; v++) R[j] = fmaf(a64[j], R[j], F[v * 64 + j * 16 + r16]);
    // apply correction: r += a^{q+1} * a^{4h} * a^{16i} * R
    float gi = p4h[j] * R[j];
#pragma unroll
    for (int i = 0; i < 4; i++) {
      acc[i][j][0] = fmaf(a1[j], gi, acc[i][j][0]);
      acc[i][j][1] = fmaf(a2[j], gi, acc[i][j][1]);
      acc[i][j][2] = fmaf(a3[j], gi, acc[i][j][2]);
      acc[i][j][3] = fmaf(a4[j], gi, acc[i][j][3]);
      gi *= a16[j];
    }
  }

  // ---- stores: r_seq ----
#pragma unroll
  for (int i = 0; i < 4; i++)
#pragma unroll
    for (int j = 0; j < 4; j++) {
      const long mrow = m0 + w * 64 + i * 16 + h * 4;
      const int  n    = n0 + j * 16 + r16;
#pragma unroll
      for (int q = 0; q < 4; q++)
        out[(mrow + q) * 1024 + n] = acc[i][j][q];
    }
  // r_final = R_3 = a^64 R_2 + C_3 (wave 3 holds R_2 in R[j])
  if (w == 3 && h == 0) {
#pragma unroll
    for (int j = 0; j < 4; j++)
      out[(1 << 22) + b * 1024 + n0 + j * 16 + r16] = fmaf(a64[j], R[j], F[192 + j * 16 + r16]);
  }
}

extern "C" void kernel_launch(void* const* d_in, const int* in_sizes, int n_in,
                              void* d_out, int out_size, void* d_ws, size_t ws_size,
                              hipStream_t stream) {
  const float* x     = (const float*)d_in[0];
  const float* r0    = (const float*)d_in[1];
  const float* W     = (const float*)d_in[2];
  const float* b     = (const float*)d_in[3];
  const float* alpha = (const float*)d_in[4];
  float* out = (float*)d_out;

  unsigned short* xm = (unsigned short*)d_ws;                        // 8 MiB: [4096][1024] bf16
  unsigned short* Wb = (unsigned short*)((char*)d_ws + (8u << 20));  // 2 MiB: [1024][1024] bf16

  k_mean<<<2048, 256, 0, stream>>>(x, xm, W, Wb);
  k_gemmscan<<<256, 256, 0, stream>>>(xm, Wb, b, r0, alpha, out);
}